// Round 1
// baseline (1028.166 us; speedup 1.0000x reference)
//
#include <hip/hip_runtime.h>
#include <cstdint>
#include <cstddef>

// Problem constants (fixed by the reference setup)
#define N_NODES 50000
#define N_EDGES 800000
#define F_INPUT 128
#define DIM 256
#define NLAYERS 3
#define NGRAPHS 512

typedef __bf16 bf16_t;
typedef bf16_t bf16x8 __attribute__((ext_vector_type(8)));
typedef float f32x4 __attribute__((ext_vector_type(4)));

__device__ __forceinline__ float bf2f(unsigned short u) {
    union { unsigned u32; float f; } x; x.u32 = ((unsigned)u) << 16; return x.f;
}
__device__ __forceinline__ unsigned short f2bf(float f) {
    union { float f; unsigned u; } x; x.f = f;
    unsigned r = (x.u + 0x7fffu + ((x.u >> 16) & 1u)) >> 16;
    return (unsigned short)r;
}

// ---- weight convert: W [layers][K][N] f32 -> hi/lo bf16 stored transposed [layers][N][K]
__global__ void k_wconv(const float* __restrict__ W, unsigned short* __restrict__ hi,
                        unsigned short* __restrict__ lo, int Kd, int Nd, int total) {
    int idx = blockIdx.x * 256 + threadIdx.x;
    if (idx >= total) return;
    int kn = Kd * Nd;
    int l = idx / kn, r = idx - l * kn;
    int k = r / Nd, n = r - k * Nd;
    float w = W[idx];
    unsigned short h = f2bf(w);
    unsigned short l16 = f2bf(w - bf2f(h));
    hi[l * kn + n * Kd + k] = h;
    lo[l * kn + n * Kd + k] = l16;
}

// ---- x f32 -> bf16 (vectorized by 4)
__global__ void k_xconv(const float* __restrict__ x, unsigned short* __restrict__ xb, int total4) {
    int i = blockIdx.x * 256 + threadIdx.x;
    if (i >= total4) return;
    float4 v = reinterpret_cast<const float4*>(x)[i];
    ushort4 o;
    o.x = f2bf(v.x); o.y = f2bf(v.y); o.z = f2bf(v.z); o.w = f2bf(v.w);
    reinterpret_cast<ushort4*>(xb)[i] = o;
}

// ---- degree histogram (by dst) + per-graph node count
__global__ void k_hist(const int* __restrict__ dst, const int* __restrict__ batch,
                       int* __restrict__ deg, int* __restrict__ cnt) {
    int i = blockIdx.x * 256 + threadIdx.x;
    if (i < N_EDGES) atomicAdd(&deg[dst[i]], 1);
    if (i < N_NODES) atomicAdd(&cnt[batch[i]], 1);
}

// ---- scan step 1: per-block inclusive scan of deg -> row_ptr[1+i] (local), block totals
__global__ void k_scan1(const int* __restrict__ deg, int* __restrict__ rp1,
                        int* __restrict__ bsum) {
    __shared__ int s[256];
    int t = threadIdx.x, b = blockIdx.x, i = b * 256 + t;
    int v = (i < N_NODES) ? deg[i] : 0;
    s[t] = v; __syncthreads();
    for (int off = 1; off < 256; off <<= 1) {
        int x = (t >= off) ? s[t - off] : 0;
        __syncthreads();
        s[t] += x;
        __syncthreads();
    }
    if (i < N_NODES) rp1[i] = s[t];
    if (t == 255) bsum[b] = s[255];
}

// ---- scan step 2 (single block, 512 thr): exclusive scan of block sums; exclusive scan of cnt -> gstart
__global__ void k_scan2(const int* __restrict__ bsum, int* __restrict__ boff,
                        const int* __restrict__ cnt, int* __restrict__ gstart, int nb) {
    __shared__ int s[512];
    int t = threadIdx.x;
    int v = (t < nb) ? bsum[t] : 0;
    s[t] = v; __syncthreads();
    for (int off = 1; off < 512; off <<= 1) {
        int x = (t >= off) ? s[t - off] : 0;
        __syncthreads(); s[t] += x; __syncthreads();
    }
    if (t < nb) boff[t] = s[t] - v;
    __syncthreads();
    int c = cnt[t];
    s[t] = c; __syncthreads();
    for (int off = 1; off < 512; off <<= 1) {
        int x = (t >= off) ? s[t - off] : 0;
        __syncthreads(); s[t] += x; __syncthreads();
    }
    gstart[t] = s[t] - c;
}

// ---- scan step 3: add block offsets; finalize row_ptr[0]
__global__ void k_scan3(int* __restrict__ row_ptr, const int* __restrict__ boff) {
    int t = threadIdx.x, b = blockIdx.x, i = b * 256 + t;
    if (i < N_NODES) row_ptr[1 + i] += boff[b];
    if (i == 0) row_ptr[0] = 0;
}

// ---- CSR fill (order within a node irrelevant for a sum)
__global__ void k_fill(const int* __restrict__ src, const int* __restrict__ dst,
                       const int* __restrict__ row_ptr, int* __restrict__ cur,
                       int* __restrict__ csr_src) {
    int e = blockIdx.x * 256 + threadIdx.x;
    if (e >= N_EDGES) return;
    int d = dst[e];
    int p = atomicAdd(&cur[d], 1);
    csr_src[row_ptr[d] + p] = src[e];
}

// ---- aggregation: z0[i] = h[i] + sum_{j->i} h[j]   (one wave per node, bf16 in/out, fp32 acc)
__global__ void k_agg(const unsigned short* __restrict__ h, const int* __restrict__ row_ptr,
                      const int* __restrict__ csr_src, unsigned short* __restrict__ z0) {
    int wid = threadIdx.x >> 6, lane = threadIdx.x & 63;
    int node = blockIdx.x * 4 + wid;
    if (node >= N_NODES) return;
    const ushort4* hp = reinterpret_cast<const ushort4*>(h);
    ushort4 own = hp[node * 64 + lane];
    float a0 = bf2f(own.x), a1 = bf2f(own.y), a2 = bf2f(own.z), a3 = bf2f(own.w);
    int e = row_ptr[node], end = row_ptr[node + 1];
    int sn = (e < end) ? csr_src[e] : 0;
    while (e < end) {
        int s = sn;
        ++e;
        if (e < end) sn = csr_src[e];
        ushort4 v = hp[s * 64 + lane];
        a0 += bf2f(v.x); a1 += bf2f(v.y); a2 += bf2f(v.z); a3 += bf2f(v.w);
    }
    ushort4 o;
    o.x = f2bf(a0); o.y = f2bf(a1); o.z = f2bf(a2); o.w = f2bf(a3);
    reinterpret_cast<ushort4*>(z0)[node * 64 + lane] = o;
}

// ---- MFMA GEMM: C[M,256] = A[M,K] @ (Whi+Wlo)^T + bias, optional relu.
// Whi/Wlo are [256][K] bf16 (K-major). 128x128x32 tiles, 4 waves x (4x4 of 16x16x32).
template <int K, bool RELU>
__global__ __launch_bounds__(256) void k_gemm(const unsigned short* __restrict__ A,
                                              const unsigned short* __restrict__ Whi,
                                              const unsigned short* __restrict__ Wlo,
                                              const float* __restrict__ bias,
                                              unsigned short* __restrict__ C, int M) {
    __shared__ __align__(16) unsigned short As[128 * 32];
    __shared__ __align__(16) unsigned short Bh[128 * 32];
    __shared__ __align__(16) unsigned short Bl[128 * 32];
    const int tid = threadIdx.x;
    const int m0 = blockIdx.x * 128;
    const int n0 = blockIdx.y * 128;
    const int wid = tid >> 6, lane = tid & 63;
    const int wm = (wid & 1) * 64, wn = (wid >> 1) * 64;
    const int lm = lane & 15, q = lane >> 4;
    const int sr = tid >> 2;   // 0..63 (staging row within half)
    const int sc = tid & 3;    // 8-elem chunk

    f32x4 acc[4][4];
#pragma unroll
    for (int i = 0; i < 4; ++i)
#pragma unroll
        for (int j = 0; j < 4; ++j) acc[i][j] = (f32x4){0.f, 0.f, 0.f, 0.f};

    for (int k0 = 0; k0 < K; k0 += 32) {
#pragma unroll
        for (int half = 0; half < 2; ++half) {
            int r = sr + half * 64;
            int arow = m0 + r;
            uint4 va = {0u, 0u, 0u, 0u};
            if (arow < M)
                va = *reinterpret_cast<const uint4*>(A + (size_t)arow * K + k0 + sc * 8);
            *reinterpret_cast<uint4*>(&As[r * 32 + sc * 8]) = va;
            uint4 vh = *reinterpret_cast<const uint4*>(Whi + (size_t)(n0 + r) * K + k0 + sc * 8);
            *reinterpret_cast<uint4*>(&Bh[r * 32 + sc * 8]) = vh;
            uint4 vl = *reinterpret_cast<const uint4*>(Wlo + (size_t)(n0 + r) * K + k0 + sc * 8);
            *reinterpret_cast<uint4*>(&Bl[r * 32 + sc * 8]) = vl;
        }
        __syncthreads();
        bf16x8 af[4], bh[4], bl[4];
#pragma unroll
        for (int i = 0; i < 4; ++i)
            af[i] = *reinterpret_cast<const bf16x8*>(&As[(wm + i * 16 + lm) * 32 + q * 8]);
#pragma unroll
        for (int j = 0; j < 4; ++j) {
            bh[j] = *reinterpret_cast<const bf16x8*>(&Bh[(wn + j * 16 + lm) * 32 + q * 8]);
            bl[j] = *reinterpret_cast<const bf16x8*>(&Bl[(wn + j * 16 + lm) * 32 + q * 8]);
        }
#pragma unroll
        for (int i = 0; i < 4; ++i)
#pragma unroll
            for (int j = 0; j < 4; ++j) {
                acc[i][j] = __builtin_amdgcn_mfma_f32_16x16x32_bf16(af[i], bl[j], acc[i][j], 0, 0, 0);
                acc[i][j] = __builtin_amdgcn_mfma_f32_16x16x32_bf16(af[i], bh[j], acc[i][j], 0, 0, 0);
            }
        __syncthreads();
    }
    float bv[4];
#pragma unroll
    for (int j = 0; j < 4; ++j) bv[j] = bias[n0 + wn + j * 16 + lm];
#pragma unroll
    for (int i = 0; i < 4; ++i) {
        int row0 = m0 + wm + i * 16 + q * 4;
#pragma unroll
        for (int j = 0; j < 4; ++j) {
            int col = n0 + wn + j * 16 + lm;
#pragma unroll
            for (int r = 0; r < 4; ++r) {
                int row = row0 + r;
                if (row < M) {
                    float v = acc[i][j][r] + bv[j];
                    if (RELU) v = fmaxf(v, 0.f);
                    C[(size_t)row * DIM + col] = f2bf(v);
                }
            }
        }
    }
}

// ---- BN statistics: column sums / sumsq with per-block partials + atomics
__global__ void k_bnstats(const unsigned short* __restrict__ z, float* __restrict__ sums) {
    int t = threadIdx.x;
    int r0 = blockIdx.x * 256;
    int rend = r0 + 256;
    if (rend > N_NODES) rend = N_NODES;
    float s = 0.f, s2 = 0.f;
    for (int r = r0; r < rend; ++r) {
        float v = bf2f(z[(size_t)r * DIM + t]);
        s += v;
        s2 = fmaf(v, v, s2);
    }
    atomicAdd(&sums[t], s);
    atomicAdd(&sums[DIM + t], s2);
}

// ---- BN apply + relu + graph mean-pool (one block per graph; batch is sorted)
__global__ void k_bnpool(const unsigned short* __restrict__ z, const float* __restrict__ sums,
                         const float* __restrict__ gamma, const float* __restrict__ beta,
                         const int* __restrict__ gstart, const int* __restrict__ cnt,
                         unsigned short* __restrict__ h, float* __restrict__ gfeat, int lofs) {
    int g = blockIdx.x, t = threadIdx.x;
    float mean = sums[t] * (1.f / N_NODES);
    float var = sums[DIM + t] * (1.f / N_NODES) - mean * mean;
    float inv = rsqrtf(var + 1e-5f);
    float ga = gamma[t], be = beta[t];
    int beg = gstart[g], c = cnt[g];
    float accv = 0.f;
    for (int r = beg; r < beg + c; ++r) {
        float v = bf2f(z[(size_t)r * DIM + t]);
        v = fmaf((v - mean) * inv, ga, be);
        v = fmaxf(v, 0.f);
        h[(size_t)r * DIM + t] = f2bf(v);
        accv += v;
    }
    float cd = (float)c;
    gfeat[g * (DIM * NLAYERS) + lofs + t] = accv / fmaxf(cd, 1.f);
}

// ---- FC head: out[g] = relu(gfeat[g] @ Wfc1 + bfc1) @ Wfc2 + bfc2   (block per graph)
__global__ void k_fc(const float* __restrict__ gfeat, const float* __restrict__ W1,
                     const float* __restrict__ b1, const float* __restrict__ W2,
                     const float* __restrict__ b2, float* __restrict__ out) {
    __shared__ float gs[DIM * NLAYERS];
    __shared__ float red[2];
    int g = blockIdx.x, t = threadIdx.x;  // 128 threads
    for (int i = t; i < DIM * NLAYERS; i += 128) gs[i] = gfeat[g * (DIM * NLAYERS) + i];
    __syncthreads();
    float acc = b1[t];
#pragma unroll 4
    for (int k = 0; k < DIM * NLAYERS; ++k) acc = fmaf(gs[k], W1[k * 128 + t], acc);
    acc = fmaxf(acc, 0.f) * W2[t];
#pragma unroll
    for (int off = 32; off > 0; off >>= 1) acc += __shfl_down(acc, off, 64);
    if ((t & 63) == 0) red[t >> 6] = acc;
    __syncthreads();
    if (t == 0) out[g] = red[0] + red[1] + b2[0];
}

extern "C" void kernel_launch(void* const* d_in, const int* in_sizes, int n_in,
                              void* d_out, int out_size, void* d_ws, size_t ws_size,
                              hipStream_t stream) {
    const float* x = (const float*)d_in[0];
    const int* ei = (const int*)d_in[1];
    const int* batch = (const int*)d_in[2];
    const float* W_enc = (const float*)d_in[4];
    const float* b_enc = (const float*)d_in[5];
    const float* W1 = (const float*)d_in[6];
    const float* b1 = (const float*)d_in[7];
    const float* W2 = (const float*)d_in[8];
    const float* b2 = (const float*)d_in[9];
    const float* gamma = (const float*)d_in[10];
    const float* beta = (const float*)d_in[11];
    const float* Wfc1 = (const float*)d_in[12];
    const float* bfc1 = (const float*)d_in[13];
    const float* Wfc2 = (const float*)d_in[14];
    const float* bfc2 = (const float*)d_in[15];
    float* out = (float*)d_out;
    const int* srcp = ei;
    const int* dstp = ei + N_EDGES;

    // Workspace bump allocator (~123 MB total)
    char* w = (char*)d_ws;
    auto alloc = [&](size_t b) -> char* {
        char* p = w;
        w += (b + 255) & ~(size_t)255;
        return p;
    };
    unsigned short* xb   = (unsigned short*)alloc((size_t)N_NODES * F_INPUT * 2);
    unsigned short* hbuf = (unsigned short*)alloc((size_t)N_NODES * DIM * 2);
    unsigned short* z0   = (unsigned short*)alloc((size_t)N_NODES * DIM * 2);
    unsigned short* tbuf = (unsigned short*)alloc((size_t)N_NODES * DIM * 2);
    unsigned short* zbuf = (unsigned short*)alloc((size_t)N_NODES * DIM * 2);
    unsigned short* wench = (unsigned short*)alloc(F_INPUT * DIM * 2);
    unsigned short* wencl = (unsigned short*)alloc(F_INPUT * DIM * 2);
    unsigned short* w1h = (unsigned short*)alloc((size_t)NLAYERS * DIM * DIM * 2);
    unsigned short* w1l = (unsigned short*)alloc((size_t)NLAYERS * DIM * DIM * 2);
    unsigned short* w2h = (unsigned short*)alloc((size_t)NLAYERS * DIM * DIM * 2);
    unsigned short* w2l = (unsigned short*)alloc((size_t)NLAYERS * DIM * DIM * 2);
    int* csr_src = (int*)alloc((size_t)N_EDGES * 4);
    int* row_ptr = (int*)alloc((size_t)(N_NODES + 1) * 4);
    size_t ctrl_bytes = sizeof(int) * (2 * N_NODES + NGRAPHS + 256 + 256) + sizeof(float) * 3 * 512;
    char* ctrl = alloc(ctrl_bytes);
    int* deg = (int*)ctrl;
    int* cur = deg + N_NODES;
    int* cnt = cur + N_NODES;
    float* bnsum = (float*)(cnt + NGRAPHS);      // 3 * 512 floats
    int* bsum = (int*)(bnsum + 3 * 512);         // 256
    int* boff = bsum + 256;                      // 256
    int* gstart = (int*)alloc(NGRAPHS * 4);
    float* gfeat = (float*)alloc((size_t)NGRAPHS * DIM * NLAYERS * 4);

    hipMemsetAsync(ctrl, 0, ctrl_bytes, stream);

    // weight prep
    k_wconv<<<(F_INPUT * DIM + 255) / 256, 256, 0, stream>>>(W_enc, wench, wencl, F_INPUT, DIM, F_INPUT * DIM);
    k_wconv<<<(NLAYERS * DIM * DIM + 255) / 256, 256, 0, stream>>>(W1, w1h, w1l, DIM, DIM, NLAYERS * DIM * DIM);
    k_wconv<<<(NLAYERS * DIM * DIM + 255) / 256, 256, 0, stream>>>(W2, w2h, w2l, DIM, DIM, NLAYERS * DIM * DIM);
    k_xconv<<<(N_NODES * F_INPUT / 4 + 255) / 256, 256, 0, stream>>>(x, xb, N_NODES * F_INPUT / 4);

    // CSR build + graph offsets
    const int NB = (N_NODES + 255) / 256;  // 196
    k_hist<<<(N_EDGES + 255) / 256, 256, 0, stream>>>(dstp, batch, deg, cnt);
    k_scan1<<<NB, 256, 0, stream>>>(deg, row_ptr + 1, bsum);
    k_scan2<<<1, 512, 0, stream>>>(bsum, boff, cnt, gstart, NB);
    k_scan3<<<NB, 256, 0, stream>>>(row_ptr, boff);
    k_fill<<<(N_EDGES + 255) / 256, 256, 0, stream>>>(srcp, dstp, row_ptr, cur, csr_src);

    // encoder: h = x @ W_enc + b_enc (no relu)
    dim3 ggrid((N_NODES + 127) / 128, 2);
    k_gemm<F_INPUT, false><<<ggrid, 256, 0, stream>>>(xb, wench, wencl, b_enc, hbuf, N_NODES);

    for (int l = 0; l < NLAYERS; ++l) {
        k_agg<<<(N_NODES + 3) / 4, 256, 0, stream>>>(hbuf, row_ptr, csr_src, z0);
        k_gemm<DIM, true><<<ggrid, 256, 0, stream>>>(z0, w1h + l * DIM * DIM, w1l + l * DIM * DIM,
                                                     b1 + l * DIM, tbuf, N_NODES);
        k_gemm<DIM, false><<<ggrid, 256, 0, stream>>>(tbuf, w2h + l * DIM * DIM, w2l + l * DIM * DIM,
                                                      b2 + l * DIM, zbuf, N_NODES);
        k_bnstats<<<NB, 256, 0, stream>>>(zbuf, bnsum + l * 512);
        k_bnpool<<<NGRAPHS, 256, 0, stream>>>(zbuf, bnsum + l * 512, gamma + l * DIM, beta + l * DIM,
                                              gstart, cnt, hbuf, gfeat, l * DIM);
    }
    k_fc<<<NGRAPHS, 128, 0, stream>>>(gfeat, Wfc1, bfc1, Wfc2, bfc2, out);
}

// Round 2
// 725.164 us; speedup vs baseline: 1.4178x; 1.4178x over previous
//
#include <hip/hip_runtime.h>
#include <cstdint>
#include <cstddef>

// Problem constants (fixed by the reference setup)
#define N_NODES 50000
#define N_PAD   50048   // 391 * 128, so GEMM A-tiles never go OOB
#define N_EDGES 800000
#define F_INPUT 128
#define DIM 256
#define NLAYERS 3
#define NGRAPHS 512

typedef __bf16 bf16_t;
typedef bf16_t bf16x8 __attribute__((ext_vector_type(8)));
typedef float f32x4 __attribute__((ext_vector_type(4)));

__device__ __forceinline__ float bf2f(unsigned short u) {
    union { unsigned u32; float f; } x; x.u32 = ((unsigned)u) << 16; return x.f;
}
__device__ __forceinline__ unsigned short f2bf(float f) {
    union { float f; unsigned u; } x; x.f = f;
    unsigned r = (x.u + 0x7fffu + ((x.u >> 16) & 1u)) >> 16;
    return (unsigned short)r;
}

// async global->LDS, 16B per lane. LDS dest must be wave-uniform base + lane*16,
// which our staging layout satisfies (thread tid <-> LDS byte offset tid*16 within half).
__device__ __forceinline__ void gl_lds16(const unsigned short* g, unsigned short* l) {
    __builtin_amdgcn_global_load_lds(
        (const __attribute__((address_space(1))) void*)g,
        (__attribute__((address_space(3))) void*)l, 16, 0, 0);
}

// ---- weight convert: W [layers][K][N] f32 -> hi/lo bf16 stored transposed [layers][N][K]
__global__ void k_wconv(const float* __restrict__ W, unsigned short* __restrict__ hi,
                        unsigned short* __restrict__ lo, int Kd, int Nd, int total) {
    int idx = blockIdx.x * 256 + threadIdx.x;
    if (idx >= total) return;
    int kn = Kd * Nd;
    int l = idx / kn, r = idx - l * kn;
    int k = r / Nd, n = r - k * Nd;
    float w = W[idx];
    unsigned short h = f2bf(w);
    unsigned short l16 = f2bf(w - bf2f(h));
    hi[l * kn + n * Kd + k] = h;
    lo[l * kn + n * Kd + k] = l16;
}

// ---- x f32 -> bf16 (vectorized by 4)
__global__ void k_xconv(const float* __restrict__ x, unsigned short* __restrict__ xb, int total4) {
    int i = blockIdx.x * 256 + threadIdx.x;
    if (i >= total4) return;
    float4 v = reinterpret_cast<const float4*>(x)[i];
    ushort4 o;
    o.x = f2bf(v.x); o.y = f2bf(v.y); o.z = f2bf(v.z); o.w = f2bf(v.w);
    reinterpret_cast<ushort4*>(xb)[i] = o;
}

// ---- degree histogram (by dst) + per-graph node count
__global__ void k_hist(const int* __restrict__ dst, const int* __restrict__ batch,
                       int* __restrict__ deg, int* __restrict__ cnt) {
    int i = blockIdx.x * 256 + threadIdx.x;
    if (i < N_EDGES) atomicAdd(&deg[dst[i]], 1);
    if (i < N_NODES) atomicAdd(&cnt[batch[i]], 1);
}

// ---- scan step 1: per-block inclusive scan of PADDED deg (round up to even) -> row_ptr[1+i]
__global__ void k_scan1(const int* __restrict__ deg, int* __restrict__ rp1,
                        int* __restrict__ bsum) {
    __shared__ int s[256];
    int t = threadIdx.x, b = blockIdx.x, i = b * 256 + t;
    int d = (i < N_NODES) ? deg[i] : 0;
    int v = d + (d & 1);   // pad each node's edge list to even length
    s[t] = v; __syncthreads();
    for (int off = 1; off < 256; off <<= 1) {
        int x = (t >= off) ? s[t - off] : 0;
        __syncthreads();
        s[t] += x;
        __syncthreads();
    }
    if (i < N_NODES) rp1[i] = s[t];
    if (t == 255) bsum[b] = s[255];
}

// ---- scan step 2 (single block, 512 thr): exclusive scan of block sums; exclusive scan of cnt -> gstart
__global__ void k_scan2(const int* __restrict__ bsum, int* __restrict__ boff,
                        const int* __restrict__ cnt, int* __restrict__ gstart, int nb) {
    __shared__ int s[512];
    int t = threadIdx.x;
    int v = (t < nb) ? bsum[t] : 0;
    s[t] = v; __syncthreads();
    for (int off = 1; off < 512; off <<= 1) {
        int x = (t >= off) ? s[t - off] : 0;
        __syncthreads(); s[t] += x; __syncthreads();
    }
    if (t < nb) boff[t] = s[t] - v;
    __syncthreads();
    int c = cnt[t];
    s[t] = c; __syncthreads();
    for (int off = 1; off < 512; off <<= 1) {
        int x = (t >= off) ? s[t - off] : 0;
        __syncthreads(); s[t] += x; __syncthreads();
    }
    gstart[t] = s[t] - c;
}

// ---- scan step 3: add block offsets; finalize row_ptr[0]
__global__ void k_scan3(int* __restrict__ row_ptr, const int* __restrict__ boff) {
    int t = threadIdx.x, b = blockIdx.x, i = b * 256 + t;
    if (i < N_NODES) row_ptr[1 + i] += boff[b];
    if (i == 0) row_ptr[0] = 0;
}

// ---- CSR fill + dummy-edge writer (dummy source = row N_NODES, which is zeroed)
__global__ void k_fill(const int* __restrict__ src, const int* __restrict__ dst,
                       const int* __restrict__ row_ptr, const int* __restrict__ deg,
                       int* __restrict__ cur, int* __restrict__ csr_src) {
    int e = blockIdx.x * 256 + threadIdx.x;
    if (e < N_EDGES) {
        int d = dst[e];
        int p = atomicAdd(&cur[d], 1);
        csr_src[row_ptr[d] + p] = src[e];
    }
    if (e < N_NODES) {
        int dg = deg[e];
        if (dg & 1) csr_src[row_ptr[e] + dg] = N_NODES;
    }
}

// ---- aggregation: z0[i] = h[i] + sum_{j->i} h[j]
// 2 nodes per wave (32 lanes x 16B each), edge loop unrolled by 2 (CSR padded even),
// index prefetch one iteration ahead for memory-level parallelism.
__global__ void k_agg(const unsigned short* __restrict__ h, const int* __restrict__ row_ptr,
                      const int* __restrict__ csr_src, unsigned short* __restrict__ z0) {
    int wid = threadIdx.x >> 6, lane = threadIdx.x & 63;
    int half = lane >> 5, cl = lane & 31;
    int node = blockIdx.x * 8 + wid * 2 + half;   // grid = 6250 blocks exactly
    const uint4* hp = reinterpret_cast<const uint4*>(h);
    uint4 own = hp[(size_t)node * 32 + cl];
    const unsigned short* op = (const unsigned short*)&own;
    float a[8];
#pragma unroll
    for (int i = 0; i < 8; ++i) a[i] = bf2f(op[i]);
    int e = row_ptr[node], end = row_ptr[node + 1];
    int s0 = 0, s1 = 0;
    if (e < end) { s0 = csr_src[e]; s1 = csr_src[e + 1]; }
    while (e < end) {
        int c0 = s0, c1 = s1;
        int en = e + 2;
        if (en < end) { s0 = csr_src[en]; s1 = csr_src[en + 1]; }
        uint4 v0 = hp[(size_t)c0 * 32 + cl];
        uint4 v1 = hp[(size_t)c1 * 32 + cl];
        e = en;
        const unsigned short* p0 = (const unsigned short*)&v0;
        const unsigned short* p1 = (const unsigned short*)&v1;
#pragma unroll
        for (int i = 0; i < 8; ++i) a[i] += bf2f(p0[i]) + bf2f(p1[i]);
    }
    uint4 o;
    unsigned short* po = (unsigned short*)&o;
#pragma unroll
    for (int i = 0; i < 8; ++i) po[i] = f2bf(a[i]);
    reinterpret_cast<uint4*>(z0)[(size_t)node * 32 + cl] = o;
}

// ---- MFMA GEMM: C[M,256] = A[M,K] @ (Whi+Wlo)^T + bias, optional relu, optional fused
// column-stats (sum, sumsq -> bnsum via atomics). A buffer padded to N_PAD rows so
// staging never masks. Whi/Wlo are [256][K] bf16 (K-major). 128x128x32 tiles,
// 4 waves x (4x4 of 16x16x32), global_load_lds(16B) staging.
template <int K, bool RELU, bool STATS>
__global__ __launch_bounds__(256) void k_gemm(const unsigned short* __restrict__ A,
                                              const unsigned short* __restrict__ Whi,
                                              const unsigned short* __restrict__ Wlo,
                                              const float* __restrict__ bias,
                                              unsigned short* __restrict__ C,
                                              float* __restrict__ bnsum, int M) {
    __shared__ __align__(16) unsigned short As[128 * 32];
    __shared__ __align__(16) unsigned short Bh[128 * 32];
    __shared__ __align__(16) unsigned short Bl[128 * 32];
    const int tid = threadIdx.x;
    const int m0 = blockIdx.x * 128;
    const int n0 = blockIdx.y * 128;
    const int wid = tid >> 6, lane = tid & 63;
    const int wm = (wid & 1) * 64, wn = (wid >> 1) * 64;
    const int lm = lane & 15, q = lane >> 4;
    const int sr = tid >> 2;   // 0..63 (staging row within half)
    const int sc = tid & 3;    // 8-elem chunk

    f32x4 acc[4][4];
#pragma unroll
    for (int i = 0; i < 4; ++i)
#pragma unroll
        for (int j = 0; j < 4; ++j) acc[i][j] = (f32x4){0.f, 0.f, 0.f, 0.f};

    for (int k0 = 0; k0 < K; k0 += 32) {
#pragma unroll
        for (int hf = 0; hf < 2; ++hf) {
            int r = sr + hf * 64;
            gl_lds16(A + (size_t)(m0 + r) * K + k0 + sc * 8, &As[r * 32 + sc * 8]);
            gl_lds16(Whi + (size_t)(n0 + r) * K + k0 + sc * 8, &Bh[r * 32 + sc * 8]);
            gl_lds16(Wlo + (size_t)(n0 + r) * K + k0 + sc * 8, &Bl[r * 32 + sc * 8]);
        }
        __syncthreads();
        bf16x8 af[4], bh[4], bl[4];
#pragma unroll
        for (int i = 0; i < 4; ++i)
            af[i] = *reinterpret_cast<const bf16x8*>(&As[(wm + i * 16 + lm) * 32 + q * 8]);
#pragma unroll
        for (int j = 0; j < 4; ++j) {
            bh[j] = *reinterpret_cast<const bf16x8*>(&Bh[(wn + j * 16 + lm) * 32 + q * 8]);
            bl[j] = *reinterpret_cast<const bf16x8*>(&Bl[(wn + j * 16 + lm) * 32 + q * 8]);
        }
#pragma unroll
        for (int i = 0; i < 4; ++i)
#pragma unroll
            for (int j = 0; j < 4; ++j) {
                acc[i][j] = __builtin_amdgcn_mfma_f32_16x16x32_bf16(af[i], bl[j], acc[i][j], 0, 0, 0);
                acc[i][j] = __builtin_amdgcn_mfma_f32_16x16x32_bf16(af[i], bh[j], acc[i][j], 0, 0, 0);
            }
        __syncthreads();
    }
    float bv[4];
#pragma unroll
    for (int j = 0; j < 4; ++j) bv[j] = bias[n0 + wn + j * 16 + lm];
#pragma unroll
    for (int j = 0; j < 4; ++j) {
        int col = n0 + wn + j * 16 + lm;
        float s = 0.f, s2 = 0.f;
#pragma unroll
        for (int i = 0; i < 4; ++i) {
            int row0 = m0 + wm + i * 16 + q * 4;
#pragma unroll
            for (int r = 0; r < 4; ++r) {
                int row = row0 + r;
                if (row < M) {
                    float v = acc[i][j][r] + bv[j];
                    if (STATS) { s += v; s2 = fmaf(v, v, s2); }
                    if (RELU) v = fmaxf(v, 0.f);
                    C[(size_t)row * DIM + col] = f2bf(v);
                }
            }
        }
        if (STATS) {
            s += __shfl_xor(s, 16); s += __shfl_xor(s, 32);
            s2 += __shfl_xor(s2, 16); s2 += __shfl_xor(s2, 32);
            if (q == 0) {
                atomicAdd(&bnsum[col], s);
                atomicAdd(&bnsum[DIM + col], s2);
            }
        }
    }
}

// ---- BN apply + relu + graph mean-pool (grid = graphs x 4 row-splits; batch is sorted)
__global__ void k_bnpool(const unsigned short* __restrict__ z, const float* __restrict__ sums,
                         const float* __restrict__ gamma, const float* __restrict__ beta,
                         const int* __restrict__ gstart, const int* __restrict__ cnt,
                         unsigned short* __restrict__ h, float* __restrict__ gfeat, int lofs) {
    int g = blockIdx.x, sp = blockIdx.y, t = threadIdx.x;
    float mean = sums[t] * (1.f / N_NODES);
    float var = sums[DIM + t] * (1.f / N_NODES) - mean * mean;
    float inv = rsqrtf(var + 1e-5f);
    float ga = gamma[t], be = beta[t];
    int beg = gstart[g], c = cnt[g];
    int chunk = (c + 3) >> 2;
    int r0 = beg + sp * chunk;
    int r1 = beg + c;
    int rlim = r0 + chunk;
    if (rlim < r1) r1 = rlim;
    float accv = 0.f;
    for (int r = r0; r < r1; ++r) {
        float v = bf2f(z[(size_t)r * DIM + t]);
        v = fmaf((v - mean) * inv, ga, be);
        v = fmaxf(v, 0.f);
        h[(size_t)r * DIM + t] = f2bf(v);
        accv += v;
    }
    atomicAdd(&gfeat[g * (DIM * NLAYERS) + lofs + t], accv / fmaxf((float)c, 1.f));
}

// ---- FC head: out[g] = relu(gfeat[g] @ Wfc1 + bfc1) @ Wfc2 + bfc2
// block per graph, 1024 threads: 128 outputs x 8 k-splits of 96
__global__ __launch_bounds__(1024) void k_fc(const float* __restrict__ gfeat,
                                             const float* __restrict__ W1,
                                             const float* __restrict__ b1,
                                             const float* __restrict__ W2,
                                             const float* __restrict__ b2,
                                             float* __restrict__ out) {
    __shared__ float gs[DIM * NLAYERS];
    __shared__ float part[8][128];
    __shared__ float red2[2];
    int g = blockIdx.x, t = threadIdx.x;
    int o = t & 127, kk = t >> 7;
    for (int i = t; i < DIM * NLAYERS; i += 1024) gs[i] = gfeat[g * (DIM * NLAYERS) + i];
    __syncthreads();
    float acc = 0.f;
    const float* wp = W1 + (size_t)(kk * 96) * 128 + o;
#pragma unroll 4
    for (int k = 0; k < 96; ++k) acc = fmaf(gs[kk * 96 + k], wp[(size_t)k * 128], acc);
    part[kk][o] = acc;
    __syncthreads();
    if (t < 128) {
        float v = b1[o];
#pragma unroll
        for (int p = 0; p < 8; ++p) v += part[p][o];
        v = fmaxf(v, 0.f) * W2[o];
#pragma unroll
        for (int off = 32; off; off >>= 1) v += __shfl_down(v, off, 64);
        if ((t & 63) == 0) red2[t >> 6] = v;
    }
    __syncthreads();
    if (t == 0) out[g] = red2[0] + red2[1] + b2[0];
}

extern "C" void kernel_launch(void* const* d_in, const int* in_sizes, int n_in,
                              void* d_out, int out_size, void* d_ws, size_t ws_size,
                              hipStream_t stream) {
    const float* x = (const float*)d_in[0];
    const int* ei = (const int*)d_in[1];
    const int* batch = (const int*)d_in[2];
    const float* W_enc = (const float*)d_in[4];
    const float* b_enc = (const float*)d_in[5];
    const float* W1 = (const float*)d_in[6];
    const float* b1 = (const float*)d_in[7];
    const float* W2 = (const float*)d_in[8];
    const float* b2 = (const float*)d_in[9];
    const float* gamma = (const float*)d_in[10];
    const float* beta = (const float*)d_in[11];
    const float* Wfc1 = (const float*)d_in[12];
    const float* bfc1 = (const float*)d_in[13];
    const float* Wfc2 = (const float*)d_in[14];
    const float* bfc2 = (const float*)d_in[15];
    float* out = (float*)d_out;
    const int* srcp = ei;
    const int* dstp = ei + N_EDGES;

    // Workspace bump allocator (~125 MB total)
    char* w = (char*)d_ws;
    auto alloc = [&](size_t b) -> char* {
        char* p = w;
        w += (b + 255) & ~(size_t)255;
        return p;
    };
    unsigned short* xb   = (unsigned short*)alloc((size_t)N_PAD * F_INPUT * 2);
    unsigned short* hbuf = (unsigned short*)alloc((size_t)N_PAD * DIM * 2);
    unsigned short* z0   = (unsigned short*)alloc((size_t)N_PAD * DIM * 2);
    unsigned short* tbuf = (unsigned short*)alloc((size_t)N_PAD * DIM * 2);
    unsigned short* zbuf = (unsigned short*)alloc((size_t)N_PAD * DIM * 2);
    unsigned short* wench = (unsigned short*)alloc(F_INPUT * DIM * 2);
    unsigned short* wencl = (unsigned short*)alloc(F_INPUT * DIM * 2);
    unsigned short* w1h = (unsigned short*)alloc((size_t)NLAYERS * DIM * DIM * 2);
    unsigned short* w1l = (unsigned short*)alloc((size_t)NLAYERS * DIM * DIM * 2);
    unsigned short* w2h = (unsigned short*)alloc((size_t)NLAYERS * DIM * DIM * 2);
    unsigned short* w2l = (unsigned short*)alloc((size_t)NLAYERS * DIM * DIM * 2);
    int* csr_src = (int*)alloc((size_t)(N_EDGES + N_NODES) * 4);
    int* row_ptr = (int*)alloc((size_t)(N_NODES + 1) * 4);
    size_t ctrl_bytes = sizeof(int) * (2 * N_NODES + NGRAPHS + 256 + 256) + sizeof(float) * 3 * 512;
    char* ctrl = alloc(ctrl_bytes);
    int* deg = (int*)ctrl;
    int* cur = deg + N_NODES;
    int* cnt = cur + N_NODES;
    float* bnsum = (float*)(cnt + NGRAPHS);      // 3 * 512 floats
    int* bsum = (int*)(bnsum + 3 * 512);         // 256
    int* boff = bsum + 256;                      // 256
    int* gstart = (int*)alloc(NGRAPHS * 4);
    float* gfeat = (float*)alloc((size_t)NGRAPHS * DIM * NLAYERS * 4);

    hipMemsetAsync(ctrl, 0, ctrl_bytes, stream);
    hipMemsetAsync(gfeat, 0, (size_t)NGRAPHS * DIM * NLAYERS * 4, stream);
    // zero the dummy row (index N_NODES) of hbuf so padded CSR edges add exact 0
    hipMemsetAsync(hbuf + (size_t)N_NODES * DIM, 0, DIM * 2, stream);

    // weight prep
    k_wconv<<<(F_INPUT * DIM + 255) / 256, 256, 0, stream>>>(W_enc, wench, wencl, F_INPUT, DIM, F_INPUT * DIM);
    k_wconv<<<(NLAYERS * DIM * DIM + 255) / 256, 256, 0, stream>>>(W1, w1h, w1l, DIM, DIM, NLAYERS * DIM * DIM);
    k_wconv<<<(NLAYERS * DIM * DIM + 255) / 256, 256, 0, stream>>>(W2, w2h, w2l, DIM, DIM, NLAYERS * DIM * DIM);
    k_xconv<<<(N_NODES * F_INPUT / 4 + 255) / 256, 256, 0, stream>>>(x, xb, N_NODES * F_INPUT / 4);

    // CSR build + graph offsets
    const int NB = (N_NODES + 255) / 256;  // 196
    k_hist<<<(N_EDGES + 255) / 256, 256, 0, stream>>>(dstp, batch, deg, cnt);
    k_scan1<<<NB, 256, 0, stream>>>(deg, row_ptr + 1, bsum);
    k_scan2<<<1, 512, 0, stream>>>(bsum, boff, cnt, gstart, NB);
    k_scan3<<<NB, 256, 0, stream>>>(row_ptr, boff);
    k_fill<<<(N_EDGES + 255) / 256, 256, 0, stream>>>(srcp, dstp, row_ptr, deg, cur, csr_src);

    // encoder: h = x @ W_enc + b_enc (no relu, no stats)
    dim3 ggrid((N_NODES + 127) / 128, 2);
    k_gemm<F_INPUT, false, false><<<ggrid, 256, 0, stream>>>(xb, wench, wencl, b_enc, hbuf,
                                                             nullptr, N_NODES);

    dim3 pgrid(NGRAPHS, 4);
    for (int l = 0; l < NLAYERS; ++l) {
        k_agg<<<N_NODES / 8, 256, 0, stream>>>(hbuf, row_ptr, csr_src, z0);
        k_gemm<DIM, true, false><<<ggrid, 256, 0, stream>>>(z0, w1h + l * DIM * DIM, w1l + l * DIM * DIM,
                                                            b1 + l * DIM, tbuf, nullptr, N_NODES);
        k_gemm<DIM, false, true><<<ggrid, 256, 0, stream>>>(tbuf, w2h + l * DIM * DIM, w2l + l * DIM * DIM,
                                                            b2 + l * DIM, zbuf, bnsum + l * 512, N_NODES);
        k_bnpool<<<pgrid, 256, 0, stream>>>(zbuf, bnsum + l * 512, gamma + l * DIM, beta + l * DIM,
                                            gstart, cnt, hbuf, gfeat, l * DIM);
    }
    k_fc<<<NGRAPHS, 1024, 0, stream>>>(gfeat, Wfc1, bfc1, Wfc2, bfc2, out);
}

// Round 4
// 712.507 us; speedup vs baseline: 1.4430x; 1.0178x over previous
//
#include <hip/hip_runtime.h>
#include <cstdint>
#include <cstddef>

// Problem constants (fixed by the reference setup)
#define N_NODES 50000
#define N_PAD   50048   // 391 * 128, so GEMM A-tiles never go OOB
#define N_EDGES 800000
#define F_INPUT 128
#define DIM 256
#define NLAYERS 3
#define NGRAPHS 512
#define NBH 64          // histogram/fill blocks
#define EPB 12500       // edges per histogram block (64*12500 = 800000)

typedef __bf16 bf16_t;
typedef bf16_t bf16x8 __attribute__((ext_vector_type(8)));
typedef float f32x4 __attribute__((ext_vector_type(4)));

__device__ __forceinline__ float bf2f(unsigned short u) {
    union { unsigned u32; float f; } x; x.u32 = ((unsigned)u) << 16; return x.f;
}
__device__ __forceinline__ unsigned short f2bf(float f) {
    union { float f; unsigned u; } x; x.f = f;
    unsigned r = (x.u + 0x7fffu + ((x.u >> 16) & 1u)) >> 16;
    return (unsigned short)r;
}

__device__ __forceinline__ void gl_lds16(const unsigned short* g, unsigned short* l) {
    __builtin_amdgcn_global_load_lds(
        (const __attribute__((address_space(1))) void*)g,
        (__attribute__((address_space(3))) void*)l, 16, 0, 0);
}

// ---- merged prep: weight hi/lo split+transpose AND x f32->bf16
// NOTE: must be launched with >= 6250 blocks (x conversion needs 1.6M threads).
__global__ void k_prep(const float* __restrict__ W_enc, const float* __restrict__ W1,
                       const float* __restrict__ W2, const float* __restrict__ x,
                       unsigned short* __restrict__ wench, unsigned short* __restrict__ wencl,
                       unsigned short* __restrict__ w1h, unsigned short* __restrict__ w1l,
                       unsigned short* __restrict__ w2h, unsigned short* __restrict__ w2l,
                       unsigned short* __restrict__ xb) {
    int idx = blockIdx.x * 256 + threadIdx.x;
    if (idx < 32768) {                       // W_enc [128][256] -> [256][128] hi/lo
        float w = W_enc[idx];
        int k = idx >> 8, n = idx & 255;
        unsigned short h = f2bf(w), lo = f2bf(w - bf2f(h));
        wench[n * 128 + k] = h; wencl[n * 128 + k] = lo;
    } else if (idx < 32768 + 196608) {       // W1 [3][256][256] -> [3][256][256]^T
        int j = idx - 32768;
        int l = j >> 16, r = j & 65535, k = r >> 8, n = r & 255;
        float w = W1[j];
        unsigned short h = f2bf(w), lo = f2bf(w - bf2f(h));
        w1h[l * 65536 + n * 256 + k] = h; w1l[l * 65536 + n * 256 + k] = lo;
    } else if (idx < 32768 + 2 * 196608) {   // W2
        int j = idx - 32768 - 196608;
        int l = j >> 16, r = j & 65535, k = r >> 8, n = r & 255;
        float w = W2[j];
        unsigned short h = f2bf(w), lo = f2bf(w - bf2f(h));
        w2h[l * 65536 + n * 256 + k] = h; w2l[l * 65536 + n * 256 + k] = lo;
    }
    if (idx < (N_NODES * F_INPUT) / 4) {     // x -> bf16, 4 at a time (1,600,000 iters)
        float4 v = reinterpret_cast<const float4*>(x)[idx];
        ushort4 o;
        o.x = f2bf(v.x); o.y = f2bf(v.y); o.z = f2bf(v.z); o.w = f2bf(v.w);
        reinterpret_cast<ushort4*>(xb)[idx] = o;
    }
}

// ---- per-block LDS histogram of dst (packed 2x16-bit, 2 node-range passes), no global atomics
__global__ __launch_bounds__(512) void k_count(const int* __restrict__ dst,
                                               unsigned* __restrict__ slab) {
    __shared__ unsigned bins[16384];   // 64 KB
    int b = blockIdx.x, t = threadIdx.x;
    int e0 = b * EPB, e1 = e0 + EPB;
    for (int pass = 0; pass < 2; ++pass) {
        int lo = pass << 15;
        int words = pass ? 8616 : 16384;   // pass1 covers nodes [32768,50000)
        for (int w = t; w < 16384; w += 512) bins[w] = 0;
        __syncthreads();
        for (int e = e0 + t; e < e1; e += 512) {
            int r = dst[e] - lo;
            if ((unsigned)r < 32768u)
                atomicAdd(&bins[r >> 1], 1u << ((r & 1) * 16));
        }
        __syncthreads();
        unsigned* out = slab + b * 25000 + (pass ? 16384 : 0);
        for (int w = t; w < words; w += 512) out[w] = bins[w];
        __syncthreads();
    }
}

// ---- reduce count slabs -> deg; graph boundaries from sorted batch -> gstart (no atomics)
__global__ void k_degred(const unsigned* __restrict__ slab, const int* __restrict__ batch,
                         int* __restrict__ deg, int* __restrict__ gstart) {
    int i = blockIdx.x * 256 + threadIdx.x;
    if (i < 25000) {
        unsigned s = 0;
#pragma unroll 8
        for (int b = 0; b < NBH; ++b) s += slab[b * 25000 + i];
        deg[2 * i] = s & 0xffff;
        deg[2 * i + 1] = s >> 16;
    }
    if (i < N_NODES) {
        int bt = batch[i];
        int pb = (i == 0) ? -1 : batch[i - 1];
        if (bt != pb)
            for (int g = pb + 1; g <= bt; ++g) gstart[g] = i;
        if (i == N_NODES - 1)
            for (int g = bt + 1; g <= NGRAPHS; ++g) gstart[g] = N_NODES;
    }
}

// ---- scan step 1: per-block inclusive scan of PADDED deg (round up to even)
__global__ void k_scan1(const int* __restrict__ deg, int* __restrict__ rp1,
                        int* __restrict__ bsum) {
    __shared__ int s[256];
    int t = threadIdx.x, b = blockIdx.x, i = b * 256 + t;
    int d = (i < N_NODES) ? deg[i] : 0;
    int v = d + (d & 1);
    s[t] = v; __syncthreads();
    for (int off = 1; off < 256; off <<= 1) {
        int x = (t >= off) ? s[t - off] : 0;
        __syncthreads(); s[t] += x; __syncthreads();
    }
    if (i < N_NODES) rp1[i] = s[t];
    if (t == 255) bsum[b] = s[255];
}

// ---- scan step 2: exclusive scan of block sums
__global__ void k_scan2(const int* __restrict__ bsum, int* __restrict__ boff, int nb) {
    __shared__ int s[256];
    int t = threadIdx.x;
    int v = (t < nb) ? bsum[t] : 0;
    s[t] = v; __syncthreads();
    for (int off = 1; off < 256; off <<= 1) {
        int x = (t >= off) ? s[t - off] : 0;
        __syncthreads(); s[t] += x; __syncthreads();
    }
    if (t < nb) boff[t] = s[t] - v;
}

// ---- scan step 3: add block offsets; finalize row_ptr[0]
__global__ void k_scan3(int* __restrict__ row_ptr, const int* __restrict__ boff) {
    int t = threadIdx.x, b = blockIdx.x, i = b * 256 + t;
    if (i < N_NODES) row_ptr[1 + i] += boff[b];
    if (i == 0) row_ptr[0] = 0;
}

// ---- per-(block,node) exclusive bases from count slabs; write dummy pad edge
__global__ void k_base(const unsigned* __restrict__ slab, const int* __restrict__ row_ptr,
                       int* __restrict__ base, int* __restrict__ csr_src) {
    int n = blockIdx.x * 256 + threadIdx.x;
    if (n >= N_NODES) return;
    int w = n >> 1, sh = (n & 1) * 16;
    int cur = row_ptr[n];
    int start = cur;
#pragma unroll 4
    for (int b = 0; b < NBH; ++b) {
        base[b * N_NODES + n] = cur;
        cur += (slab[b * 25000 + w] >> sh) & 0xffff;
    }
    if ((cur - start) & 1) csr_src[cur] = N_NODES;   // pad odd degree with zero-row edge
}

// ---- CSR fill with LDS cursors (no global atomics)
__global__ __launch_bounds__(512) void k_fill2(const int* __restrict__ src,
                                               const int* __restrict__ dst,
                                               const int* __restrict__ base,
                                               int* __restrict__ csr_src) {
    __shared__ unsigned bins[16384];
    int b = blockIdx.x, t = threadIdx.x;
    int e0 = b * EPB, e1 = e0 + EPB;
    for (int pass = 0; pass < 2; ++pass) {
        int lo = pass << 15;
        for (int w = t; w < 16384; w += 512) bins[w] = 0;
        __syncthreads();
        for (int e = e0 + t; e < e1; e += 512) {
            int d = dst[e];
            int r = d - lo;
            if ((unsigned)r < 32768u) {
                int sh = (r & 1) * 16;
                unsigned old = atomicAdd(&bins[r >> 1], 1u << sh);
                int local = (old >> sh) & 0xffff;
                csr_src[base[b * N_NODES + d] + local] = src[e];
            }
        }
        __syncthreads();
    }
}

// ---- aggregation: z0[i] = h[i] + sum_{j->i} h[j]; 2 nodes/wave, 16B lanes, unroll-2
__global__ void k_agg(const unsigned short* __restrict__ h, const int* __restrict__ row_ptr,
                      const int* __restrict__ csr_src, unsigned short* __restrict__ z0) {
    int wid = threadIdx.x >> 6, lane = threadIdx.x & 63;
    int half = lane >> 5, cl = lane & 31;
    int node = blockIdx.x * 8 + wid * 2 + half;
    const uint4* hp = reinterpret_cast<const uint4*>(h);
    uint4 own = hp[(size_t)node * 32 + cl];
    const unsigned short* op = (const unsigned short*)&own;
    float a[8];
#pragma unroll
    for (int i = 0; i < 8; ++i) a[i] = bf2f(op[i]);
    int e = row_ptr[node], end = row_ptr[node + 1];
    int s0 = 0, s1 = 0;
    if (e < end) { s0 = csr_src[e]; s1 = csr_src[e + 1]; }
    while (e < end) {
        int c0 = s0, c1 = s1;
        int en = e + 2;
        if (en < end) { s0 = csr_src[en]; s1 = csr_src[en + 1]; }
        uint4 v0 = hp[(size_t)c0 * 32 + cl];
        uint4 v1 = hp[(size_t)c1 * 32 + cl];
        e = en;
        const unsigned short* p0 = (const unsigned short*)&v0;
        const unsigned short* p1 = (const unsigned short*)&v1;
#pragma unroll
        for (int i = 0; i < 8; ++i) a[i] += bf2f(p0[i]) + bf2f(p1[i]);
    }
    uint4 o;
    unsigned short* po = (unsigned short*)&o;
#pragma unroll
    for (int i = 0; i < 8; ++i) po[i] = f2bf(a[i]);
    reinterpret_cast<uint4*>(z0)[(size_t)node * 32 + cl] = o;
}

// ---- MFMA GEMM with optional fused column-stat slab writes (no atomics)
template <int K, bool RELU, bool STATS>
__global__ __launch_bounds__(256) void k_gemm(const unsigned short* __restrict__ A,
                                              const unsigned short* __restrict__ Whi,
                                              const unsigned short* __restrict__ Wlo,
                                              const float* __restrict__ bias,
                                              unsigned short* __restrict__ C,
                                              float* __restrict__ statsbuf, int M) {
    __shared__ __align__(16) unsigned short As[128 * 32];
    __shared__ __align__(16) unsigned short Bh[128 * 32];
    __shared__ __align__(16) unsigned short Bl[128 * 32];
    __shared__ float st[2][2][128];
    const int tid = threadIdx.x;
    const int m0 = blockIdx.x * 128;
    const int n0 = blockIdx.y * 128;
    const int wid = tid >> 6, lane = tid & 63;
    const int wm = (wid & 1) * 64, wn = (wid >> 1) * 64;
    const int lm = lane & 15, q = lane >> 4;
    const int sr = tid >> 2;
    const int sc = tid & 3;

    f32x4 acc[4][4];
#pragma unroll
    for (int i = 0; i < 4; ++i)
#pragma unroll
        for (int j = 0; j < 4; ++j) acc[i][j] = (f32x4){0.f, 0.f, 0.f, 0.f};

    for (int k0 = 0; k0 < K; k0 += 32) {
#pragma unroll
        for (int hf = 0; hf < 2; ++hf) {
            int r = sr + hf * 64;
            gl_lds16(A + (size_t)(m0 + r) * K + k0 + sc * 8, &As[r * 32 + sc * 8]);
            gl_lds16(Whi + (size_t)(n0 + r) * K + k0 + sc * 8, &Bh[r * 32 + sc * 8]);
            gl_lds16(Wlo + (size_t)(n0 + r) * K + k0 + sc * 8, &Bl[r * 32 + sc * 8]);
        }
        __syncthreads();
        bf16x8 af[4], bh[4], bl[4];
#pragma unroll
        for (int i = 0; i < 4; ++i)
            af[i] = *reinterpret_cast<const bf16x8*>(&As[(wm + i * 16 + lm) * 32 + q * 8]);
#pragma unroll
        for (int j = 0; j < 4; ++j) {
            bh[j] = *reinterpret_cast<const bf16x8*>(&Bh[(wn + j * 16 + lm) * 32 + q * 8]);
            bl[j] = *reinterpret_cast<const bf16x8*>(&Bl[(wn + j * 16 + lm) * 32 + q * 8]);
        }
#pragma unroll
        for (int i = 0; i < 4; ++i)
#pragma unroll
            for (int j = 0; j < 4; ++j) {
                acc[i][j] = __builtin_amdgcn_mfma_f32_16x16x32_bf16(af[i], bl[j], acc[i][j], 0, 0, 0);
                acc[i][j] = __builtin_amdgcn_mfma_f32_16x16x32_bf16(af[i], bh[j], acc[i][j], 0, 0, 0);
            }
        __syncthreads();
    }
    float bv[4];
#pragma unroll
    for (int j = 0; j < 4; ++j) bv[j] = bias[n0 + wn + j * 16 + lm];
#pragma unroll
    for (int j = 0; j < 4; ++j) {
        int col = n0 + wn + j * 16 + lm;
        float s = 0.f, s2 = 0.f;
#pragma unroll
        for (int i = 0; i < 4; ++i) {
            int row0 = m0 + wm + i * 16 + q * 4;
#pragma unroll
            for (int r = 0; r < 4; ++r) {
                int row = row0 + r;
                if (row < M) {
                    float v = acc[i][j][r] + bv[j];
                    if (STATS) { s += v; s2 = fmaf(v, v, s2); }
                    if (RELU) v = fmaxf(v, 0.f);
                    C[(size_t)row * DIM + col] = f2bf(v);
                }
            }
        }
        if (STATS) {
            s += __shfl_xor(s, 16); s += __shfl_xor(s, 32);
            s2 += __shfl_xor(s2, 16); s2 += __shfl_xor(s2, 32);
            if (q == 0) {
                st[0][wid & 1][wn + j * 16 + lm] = s;
                st[1][wid & 1][wn + j * 16 + lm] = s2;
            }
        }
    }
    if (STATS) {
        __syncthreads();
        if (tid < 256) {
            int sel = tid >> 7, cl = tid & 127;
            float v = st[sel][0][cl] + st[sel][1][cl];
            statsbuf[(size_t)(blockIdx.y * gridDim.x + blockIdx.x) * 256 + sel * 128 + cl] = v;
        }
    }
}

// ---- reduce per-block stat slabs -> bnsum[512] for one layer
__global__ __launch_bounds__(512) void k_statred(const float* __restrict__ statsbuf,
                                                 float* __restrict__ bnsum, int nblk) {
    int t = threadIdx.x;           // 512
    int is2 = t >> 8, c = t & 255;
    int by = c >> 7, cl = c & 127;
    float s = 0.f;
#pragma unroll 4
    for (int b = 0; b < nblk; ++b)
        s += statsbuf[(size_t)(by * nblk + b) * 256 + is2 * 128 + cl];
    bnsum[is2 * 256 + c] = s;
}

// ---- BN apply + relu + graph mean-pool partials (slab write, no atomics)
__global__ void k_bnpool(const unsigned short* __restrict__ z, const float* __restrict__ sums,
                         const float* __restrict__ gamma, const float* __restrict__ beta,
                         const int* __restrict__ gstart,
                         unsigned short* __restrict__ h, float* __restrict__ partl) {
    int g = blockIdx.x, sp = blockIdx.y, t = threadIdx.x;
    float mean = sums[t] * (1.f / N_NODES);
    float var = sums[DIM + t] * (1.f / N_NODES) - mean * mean;
    float inv = rsqrtf(var + 1e-5f);
    float ga = gamma[t], be = beta[t];
    int beg = gstart[g], c = gstart[g + 1] - beg;
    int chunk = (c + 3) >> 2;
    int r0 = beg + sp * chunk;
    int r1 = beg + c;
    int rlim = r0 + chunk;
    if (rlim < r1) r1 = rlim;
    float accv = 0.f;
    for (int r = r0; r < r1; ++r) {
        float v = bf2f(z[(size_t)r * DIM + t]);
        v = fmaf((v - mean) * inv, ga, be);
        v = fmaxf(v, 0.f);
        h[(size_t)r * DIM + t] = f2bf(v);
        accv += v;
    }
    partl[(size_t)(g * 4 + sp) * 256 + t] = accv;
}

// ---- FC head: sums pool partials, divides by cnt, 2-layer MLP
__global__ __launch_bounds__(1024) void k_fc(const float* __restrict__ part,
                                             const int* __restrict__ gstart,
                                             const float* __restrict__ W1,
                                             const float* __restrict__ b1,
                                             const float* __restrict__ W2,
                                             const float* __restrict__ b2,
                                             float* __restrict__ out) {
    __shared__ float gs[DIM * NLAYERS];
    __shared__ float pt[8][128];
    __shared__ float red2[2];
    int g = blockIdx.x, t = threadIdx.x;
    float invc = 1.f / fmaxf((float)(gstart[g + 1] - gstart[g]), 1.f);
    for (int i = t; i < DIM * NLAYERS; i += 1024) {
        int l = i >> 8, c = i & 255;
        const float* pl = part + ((size_t)(l * NGRAPHS + g) * 4) * 256 + c;
        gs[i] = (pl[0] + pl[256] + pl[512] + pl[768]) * invc;
    }
    __syncthreads();
    int o = t & 127, kk = t >> 7;
    float acc = 0.f;
    const float* wp = W1 + (size_t)(kk * 96) * 128 + o;
#pragma unroll 4
    for (int k = 0; k < 96; ++k) acc = fmaf(gs[kk * 96 + k], wp[(size_t)k * 128], acc);
    pt[kk][o] = acc;
    __syncthreads();
    if (t < 128) {
        float v = b1[o];
#pragma unroll
        for (int p = 0; p < 8; ++p) v += pt[p][o];
        v = fmaxf(v, 0.f) * W2[o];
#pragma unroll
        for (int off = 32; off; off >>= 1) v += __shfl_down(v, off, 64);
        if ((t & 63) == 0) red2[t >> 6] = v;
    }
    __syncthreads();
    if (t == 0) out[g] = red2[0] + red2[1] + b2[0];
}

extern "C" void kernel_launch(void* const* d_in, const int* in_sizes, int n_in,
                              void* d_out, int out_size, void* d_ws, size_t ws_size,
                              hipStream_t stream) {
    const float* x = (const float*)d_in[0];
    const int* ei = (const int*)d_in[1];
    const int* batch = (const int*)d_in[2];
    const float* W_enc = (const float*)d_in[4];
    const float* b_enc = (const float*)d_in[5];
    const float* W1 = (const float*)d_in[6];
    const float* b1 = (const float*)d_in[7];
    const float* W2 = (const float*)d_in[8];
    const float* b2 = (const float*)d_in[9];
    const float* gamma = (const float*)d_in[10];
    const float* beta = (const float*)d_in[11];
    const float* Wfc1 = (const float*)d_in[12];
    const float* bfc1 = (const float*)d_in[13];
    const float* Wfc2 = (const float*)d_in[14];
    const float* bfc2 = (const float*)d_in[15];
    float* out = (float*)d_out;
    const int* srcp = ei;
    const int* dstp = ei + N_EDGES;

    // Workspace bump allocator (~121 MB)
    char* w = (char*)d_ws;
    auto alloc = [&](size_t b) -> char* {
        char* p = w;
        w += (b + 255) & ~(size_t)255;
        return p;
    };
    unsigned short* xb   = (unsigned short*)alloc((size_t)N_PAD * F_INPUT * 2);
    unsigned short* hbuf = (unsigned short*)alloc((size_t)N_PAD * DIM * 2);
    unsigned short* zA   = (unsigned short*)alloc((size_t)N_PAD * DIM * 2);  // z0 and zbuf aliased
    unsigned short* tbuf = (unsigned short*)alloc((size_t)N_PAD * DIM * 2);
    unsigned short* wench = (unsigned short*)alloc(F_INPUT * DIM * 2);
    unsigned short* wencl = (unsigned short*)alloc(F_INPUT * DIM * 2);
    unsigned short* w1h = (unsigned short*)alloc((size_t)NLAYERS * DIM * DIM * 2);
    unsigned short* w1l = (unsigned short*)alloc((size_t)NLAYERS * DIM * DIM * 2);
    unsigned short* w2h = (unsigned short*)alloc((size_t)NLAYERS * DIM * DIM * 2);
    unsigned short* w2l = (unsigned short*)alloc((size_t)NLAYERS * DIM * DIM * 2);
    int* csr_src = (int*)alloc((size_t)(N_EDGES + N_NODES) * 4);
    int* row_ptr = (int*)alloc((size_t)(N_NODES + 1) * 4);
    unsigned* slab = (unsigned*)alloc((size_t)NBH * 25000 * 4);
    int* basep = (int*)alloc((size_t)NBH * N_NODES * 4);
    int* deg = (int*)alloc((size_t)N_NODES * 4);
    int* gstart = (int*)alloc((NGRAPHS + 1) * 4);
    int* bsum = (int*)alloc(256 * 4);
    int* boff = (int*)alloc(256 * 4);
    float* statsbuf = (float*)alloc((size_t)782 * 256 * 4);
    float* bnsum = (float*)alloc((size_t)NLAYERS * 512 * 4);
    float* part = (float*)alloc((size_t)NLAYERS * NGRAPHS * 4 * 256 * 4);

    // zero the dummy row (index N_NODES) of hbuf so padded CSR edges add exact 0
    hipMemsetAsync(hbuf + (size_t)N_NODES * DIM, 0, DIM * 2, stream);

    // prep: weights hi/lo + x->bf16.  6250 blocks = 1.6M threads (x conversion bound;
    // weight branches are range-guarded).  [Round-3 bug: was 1664 blocks -> 73% of xb poison]
    k_prep<<<6250, 256, 0, stream>>>(W_enc, W1, W2, x, wench, wencl, w1h, w1l, w2h, w2l, xb);

    // CSR build, atomic-free
    const int NB = (N_NODES + 255) / 256;  // 196
    k_count<<<NBH, 512, 0, stream>>>(dstp, slab);
    k_degred<<<NB, 256, 0, stream>>>(slab, batch, deg, gstart);
    k_scan1<<<NB, 256, 0, stream>>>(deg, row_ptr + 1, bsum);
    k_scan2<<<1, 256, 0, stream>>>(bsum, boff, NB);
    k_scan3<<<NB, 256, 0, stream>>>(row_ptr, boff);
    k_base<<<NB, 256, 0, stream>>>(slab, row_ptr, basep, csr_src);
    k_fill2<<<NBH, 512, 0, stream>>>(srcp, dstp, basep, csr_src);

    // encoder: h = x @ W_enc + b_enc
    dim3 ggrid((N_PAD + 127) / 128, 2);   // (391, 2)
    k_gemm<F_INPUT, false, false><<<ggrid, 256, 0, stream>>>(xb, wench, wencl, b_enc, hbuf,
                                                             nullptr, N_NODES);

    dim3 pgrid(NGRAPHS, 4);
    for (int l = 0; l < NLAYERS; ++l) {
        k_agg<<<N_NODES / 8, 256, 0, stream>>>(hbuf, row_ptr, csr_src, zA);
        k_gemm<DIM, true, false><<<ggrid, 256, 0, stream>>>(zA, w1h + l * 65536, w1l + l * 65536,
                                                            b1 + l * DIM, tbuf, nullptr, N_NODES);
        k_gemm<DIM, false, true><<<ggrid, 256, 0, stream>>>(tbuf, w2h + l * 65536, w2l + l * 65536,
                                                            b2 + l * DIM, zA, statsbuf, N_NODES);
        k_statred<<<1, 512, 0, stream>>>(statsbuf, bnsum + l * 512, 391);
        k_bnpool<<<pgrid, 256, 0, stream>>>(zA, bnsum + l * 512, gamma + l * DIM, beta + l * DIM,
                                            gstart, hbuf, part + (size_t)l * NGRAPHS * 4 * 256);
    }
    k_fc<<<NGRAPHS, 1024, 0, stream>>>(part, gstart, Wfc1, bfc1, Wfc2, bfc2, out);
}

// Round 5
// 633.941 us; speedup vs baseline: 1.6219x; 1.1239x over previous
//
#include <hip/hip_runtime.h>
#include <cstdint>
#include <cstddef>

// Problem constants (fixed by the reference setup)
#define N_NODES 50000
#define N_PAD   50048   // 391 * 128, so GEMM A-tiles never go OOB
#define N_EDGES 800000
#define F_INPUT 128
#define DIM 256
#define NLAYERS 3
#define NGRAPHS 512
#define NBH 64          // histogram/fill blocks
#define EPB 12500       // edges per histogram block (64*12500 = 800000)
#define NGB 391         // GEMM m-blocks (N_PAD/128)

typedef __bf16 bf16_t;
typedef bf16_t bf16x8 __attribute__((ext_vector_type(8)));
typedef float f32x4 __attribute__((ext_vector_type(4)));

__device__ __forceinline__ float bf2f(unsigned short u) {
    union { unsigned u32; float f; } x; x.u32 = ((unsigned)u) << 16; return x.f;
}
__device__ __forceinline__ unsigned short f2bf(float f) {
    union { float f; unsigned u; } x; x.f = f;
    unsigned r = (x.u + 0x7fffu + ((x.u >> 16) & 1u)) >> 16;
    return (unsigned short)r;
}

__device__ __forceinline__ void gl_lds16(const unsigned short* g, unsigned short* l) {
    __builtin_amdgcn_global_load_lds(
        (const __attribute__((address_space(1))) void*)g,
        (__attribute__((address_space(3))) void*)l, 16, 0, 0);
}

// ---- merged prep: weight hi/lo split+transpose AND x f32->bf16 (needs 6250 blocks)
__global__ void k_prep(const float* __restrict__ W_enc, const float* __restrict__ W1,
                       const float* __restrict__ W2, const float* __restrict__ x,
                       unsigned short* __restrict__ wench, unsigned short* __restrict__ wencl,
                       unsigned short* __restrict__ w1h, unsigned short* __restrict__ w1l,
                       unsigned short* __restrict__ w2h, unsigned short* __restrict__ w2l,
                       unsigned short* __restrict__ xb) {
    int idx = blockIdx.x * 256 + threadIdx.x;
    if (idx < 32768) {                       // W_enc [128][256] -> [256][128] hi/lo
        float w = W_enc[idx];
        int k = idx >> 8, n = idx & 255;
        unsigned short h = f2bf(w), lo = f2bf(w - bf2f(h));
        wench[n * 128 + k] = h; wencl[n * 128 + k] = lo;
    } else if (idx < 32768 + 196608) {       // W1 [3][256][256] -> [3][256][256]^T
        int j = idx - 32768;
        int l = j >> 16, r = j & 65535, k = r >> 8, n = r & 255;
        float w = W1[j];
        unsigned short h = f2bf(w), lo = f2bf(w - bf2f(h));
        w1h[l * 65536 + n * 256 + k] = h; w1l[l * 65536 + n * 256 + k] = lo;
    } else if (idx < 32768 + 2 * 196608) {   // W2
        int j = idx - 32768 - 196608;
        int l = j >> 16, r = j & 65535, k = r >> 8, n = r & 255;
        float w = W2[j];
        unsigned short h = f2bf(w), lo = f2bf(w - bf2f(h));
        w2h[l * 65536 + n * 256 + k] = h; w2l[l * 65536 + n * 256 + k] = lo;
    }
    if (idx < (N_NODES * F_INPUT) / 4) {     // x -> bf16, 4 at a time
        float4 v = reinterpret_cast<const float4*>(x)[idx];
        ushort4 o;
        o.x = f2bf(v.x); o.y = f2bf(v.y); o.z = f2bf(v.z); o.w = f2bf(v.w);
        reinterpret_cast<ushort4*>(xb)[idx] = o;
    }
}

// ---- per-block LDS histogram of dst (packed 2x16-bit, 2 node-range passes)
__global__ __launch_bounds__(512) void k_count(const int* __restrict__ dst,
                                               unsigned* __restrict__ slab) {
    __shared__ unsigned bins[16384];
    int b = blockIdx.x, t = threadIdx.x;
    int e0 = b * EPB, e1 = e0 + EPB;
    for (int pass = 0; pass < 2; ++pass) {
        int lo = pass << 15;
        int words = pass ? 8616 : 16384;
        for (int w = t; w < 16384; w += 512) bins[w] = 0;
        __syncthreads();
        for (int e = e0 + t; e < e1; e += 512) {
            int r = dst[e] - lo;
            if ((unsigned)r < 32768u)
                atomicAdd(&bins[r >> 1], 1u << ((r & 1) * 16));
        }
        __syncthreads();
        unsigned* out = slab + b * 25000 + (pass ? 16384 : 0);
        for (int w = t; w < words; w += 512) out[w] = bins[w];
        __syncthreads();
    }
}

// ---- reduce count slabs -> deg; graph boundaries from sorted batch -> gstart
__global__ void k_degred(const unsigned* __restrict__ slab, const int* __restrict__ batch,
                         int* __restrict__ deg, int* __restrict__ gstart) {
    int i = blockIdx.x * 256 + threadIdx.x;
    if (i < 25000) {
        unsigned s = 0;
#pragma unroll 8
        for (int b = 0; b < NBH; ++b) s += slab[b * 25000 + i];
        deg[2 * i] = s & 0xffff;
        deg[2 * i + 1] = s >> 16;
    }
    if (i < N_NODES) {
        int bt = batch[i];
        int pb = (i == 0) ? -1 : batch[i - 1];
        if (bt != pb)
            for (int g = pb + 1; g <= bt; ++g) gstart[g] = i;
        if (i == N_NODES - 1)
            for (int g = bt + 1; g <= NGRAPHS; ++g) gstart[g] = N_NODES;
    }
}

// ---- scan step 1: per-block inclusive scan of deg padded to multiple of 4
__global__ void k_scan1(const int* __restrict__ deg, int* __restrict__ rp1,
                        int* __restrict__ bsum) {
    __shared__ int s[256];
    int t = threadIdx.x, b = blockIdx.x, i = b * 256 + t;
    int d = (i < N_NODES) ? deg[i] : 0;
    int v = (d + 3) & ~3;    // pad each node's edge list to multiple of 4
    s[t] = v; __syncthreads();
    for (int off = 1; off < 256; off <<= 1) {
        int x = (t >= off) ? s[t - off] : 0;
        __syncthreads(); s[t] += x; __syncthreads();
    }
    if (i < N_NODES) rp1[i] = s[t];
    if (t == 255) bsum[b] = s[255];
}

// ---- scan step 2: exclusive scan of block sums
__global__ void k_scan2(const int* __restrict__ bsum, int* __restrict__ boff, int nb) {
    __shared__ int s[256];
    int t = threadIdx.x;
    int v = (t < nb) ? bsum[t] : 0;
    s[t] = v; __syncthreads();
    for (int off = 1; off < 256; off <<= 1) {
        int x = (t >= off) ? s[t - off] : 0;
        __syncthreads(); s[t] += x; __syncthreads();
    }
    if (t < nb) boff[t] = s[t] - v;
}

// ---- scan step 3: add block offsets; finalize row_ptr[0]
__global__ void k_scan3(int* __restrict__ row_ptr, const int* __restrict__ boff) {
    int t = threadIdx.x, b = blockIdx.x, i = b * 256 + t;
    if (i < N_NODES) row_ptr[1 + i] += boff[b];
    if (i == 0) row_ptr[0] = 0;
}

// ---- per-(block,node) exclusive bases from count slabs; write pad edges (src = N_NODES)
__global__ void k_base(const unsigned* __restrict__ slab, const int* __restrict__ row_ptr,
                       int* __restrict__ base, int* __restrict__ csr_src) {
    int n = blockIdx.x * 256 + threadIdx.x;
    if (n >= N_NODES) return;
    int w = n >> 1, sh = (n & 1) * 16;
    int cur = row_ptr[n];
    int start = cur;
#pragma unroll 4
    for (int b = 0; b < NBH; ++b) {
        base[b * N_NODES + n] = cur;
        cur += (slab[b * 25000 + w] >> sh) & 0xffff;
    }
    int dg = cur - start;
    int padded = (dg + 3) & ~3;
    for (int p = dg; p < padded; ++p) csr_src[start + p] = N_NODES;
}

// ---- CSR fill with LDS cursors (no global atomics)
__global__ __launch_bounds__(512) void k_fill2(const int* __restrict__ src,
                                               const int* __restrict__ dst,
                                               const int* __restrict__ base,
                                               int* __restrict__ csr_src) {
    __shared__ unsigned bins[16384];
    int b = blockIdx.x, t = threadIdx.x;
    int e0 = b * EPB, e1 = e0 + EPB;
    for (int pass = 0; pass < 2; ++pass) {
        int lo = pass << 15;
        for (int w = t; w < 16384; w += 512) bins[w] = 0;
        __syncthreads();
        for (int e = e0 + t; e < e1; e += 512) {
            int d = dst[e];
            int r = d - lo;
            if ((unsigned)r < 32768u) {
                int sh = (r & 1) * 16;
                unsigned old = atomicAdd(&bins[r >> 1], 1u << sh);
                int local = (old >> sh) & 0xffff;
                csr_src[base[b * N_NODES + d] + local] = src[e];
            }
        }
        __syncthreads();
    }
}

// ---- aggregation, optionally fused with BN-affine+relu of the input:
//   BN=false: z0[i] = zin[i] + sum_src zin[src]            (zin row N_NODES zeroed)
//   BN=true:  z0[i] = f(zin[i]) + sum_src f(zin[src]),  f(z)=relu(A[c]*z+B[c])
//             pad edges (src==N_NODES) masked to 0.
// 2 nodes/wave (32 lanes x 16B), unroll-4 with int4 index prefetch (CSR padded to x4).
template <bool BN>
__global__ void k_agg(const unsigned short* __restrict__ zin, const int* __restrict__ row_ptr,
                      const int* __restrict__ csr_src,
                      const float* __restrict__ Ap, const float* __restrict__ Bp,
                      unsigned short* __restrict__ z0) {
    int wid = threadIdx.x >> 6, lane = threadIdx.x & 63;
    int half = lane >> 5, cl = lane & 31;
    int node = blockIdx.x * 8 + wid * 2 + half;   // grid = 6250
    const uint4* hp = reinterpret_cast<const uint4*>(zin);
    float Av[8], Bv[8];
    if (BN) {
        float4 a0 = *(const float4*)(Ap + cl * 8), a1 = *(const float4*)(Ap + cl * 8 + 4);
        float4 b0 = *(const float4*)(Bp + cl * 8), b1 = *(const float4*)(Bp + cl * 8 + 4);
        Av[0] = a0.x; Av[1] = a0.y; Av[2] = a0.z; Av[3] = a0.w;
        Av[4] = a1.x; Av[5] = a1.y; Av[6] = a1.z; Av[7] = a1.w;
        Bv[0] = b0.x; Bv[1] = b0.y; Bv[2] = b0.z; Bv[3] = b0.w;
        Bv[4] = b1.x; Bv[5] = b1.y; Bv[6] = b1.z; Bv[7] = b1.w;
    }
    uint4 own = hp[(size_t)node * 32 + cl];
    const unsigned short* op = (const unsigned short*)&own;
    float a[8];
#pragma unroll
    for (int i = 0; i < 8; ++i) {
        float z = bf2f(op[i]);
        a[i] = BN ? fmaxf(fmaf(Av[i], z, Bv[i]), 0.f) : z;
    }
    int e = row_ptr[node], end = row_ptr[node + 1];
    int4 nidx = {0, 0, 0, 0};
    if (e < end) nidx = *(const int4*)(csr_src + e);
    while (e < end) {
        int4 c = nidx;
        int en = e + 4;
        if (en < end) nidx = *(const int4*)(csr_src + en);
        uint4 v0 = hp[(size_t)c.x * 32 + cl];
        uint4 v1 = hp[(size_t)c.y * 32 + cl];
        uint4 v2 = hp[(size_t)c.z * 32 + cl];
        uint4 v3 = hp[(size_t)c.w * 32 + cl];
        e = en;
        const unsigned short* p0 = (const unsigned short*)&v0;
        const unsigned short* p1 = (const unsigned short*)&v1;
        const unsigned short* p2 = (const unsigned short*)&v2;
        const unsigned short* p3 = (const unsigned short*)&v3;
        if (BN) {
            float f0 = (c.x < N_NODES) ? 1.f : 0.f;
            float f1 = (c.y < N_NODES) ? 1.f : 0.f;
            float f2 = (c.z < N_NODES) ? 1.f : 0.f;
            float f3 = (c.w < N_NODES) ? 1.f : 0.f;
#pragma unroll
            for (int i = 0; i < 8; ++i) {
                float r0 = fmaxf(fmaf(Av[i], bf2f(p0[i]), Bv[i]), 0.f);
                float r1 = fmaxf(fmaf(Av[i], bf2f(p1[i]), Bv[i]), 0.f);
                float r2 = fmaxf(fmaf(Av[i], bf2f(p2[i]), Bv[i]), 0.f);
                float r3 = fmaxf(fmaf(Av[i], bf2f(p3[i]), Bv[i]), 0.f);
                a[i] += f0 * r0 + f1 * r1 + f2 * r2 + f3 * r3;
            }
        } else {
#pragma unroll
            for (int i = 0; i < 8; ++i)
                a[i] += (bf2f(p0[i]) + bf2f(p1[i])) + (bf2f(p2[i]) + bf2f(p3[i]));
        }
    }
    uint4 o;
    unsigned short* po = (unsigned short*)&o;
#pragma unroll
    for (int i = 0; i < 8; ++i) po[i] = f2bf(a[i]);
    reinterpret_cast<uint4*>(z0)[(size_t)node * 32 + cl] = o;
}

// ---- MFMA GEMM with optional fused column-stat slab writes
template <int K, bool RELU, bool STATS>
__global__ __launch_bounds__(256) void k_gemm(const unsigned short* __restrict__ A,
                                              const unsigned short* __restrict__ Whi,
                                              const unsigned short* __restrict__ Wlo,
                                              const float* __restrict__ bias,
                                              unsigned short* __restrict__ C,
                                              float* __restrict__ statsbuf, int M) {
    __shared__ __align__(16) unsigned short As[128 * 32];
    __shared__ __align__(16) unsigned short Bh[128 * 32];
    __shared__ __align__(16) unsigned short Bl[128 * 32];
    __shared__ float st[2][2][128];
    const int tid = threadIdx.x;
    const int m0 = blockIdx.x * 128;
    const int n0 = blockIdx.y * 128;
    const int wid = tid >> 6, lane = tid & 63;
    const int wm = (wid & 1) * 64, wn = (wid >> 1) * 64;
    const int lm = lane & 15, q = lane >> 4;
    const int sr = tid >> 2;
    const int sc = tid & 3;

    f32x4 acc[4][4];
#pragma unroll
    for (int i = 0; i < 4; ++i)
#pragma unroll
        for (int j = 0; j < 4; ++j) acc[i][j] = (f32x4){0.f, 0.f, 0.f, 0.f};

    for (int k0 = 0; k0 < K; k0 += 32) {
#pragma unroll
        for (int hf = 0; hf < 2; ++hf) {
            int r = sr + hf * 64;
            gl_lds16(A + (size_t)(m0 + r) * K + k0 + sc * 8, &As[r * 32 + sc * 8]);
            gl_lds16(Whi + (size_t)(n0 + r) * K + k0 + sc * 8, &Bh[r * 32 + sc * 8]);
            gl_lds16(Wlo + (size_t)(n0 + r) * K + k0 + sc * 8, &Bl[r * 32 + sc * 8]);
        }
        __syncthreads();
        bf16x8 af[4], bh[4], bl[4];
#pragma unroll
        for (int i = 0; i < 4; ++i)
            af[i] = *reinterpret_cast<const bf16x8*>(&As[(wm + i * 16 + lm) * 32 + q * 8]);
#pragma unroll
        for (int j = 0; j < 4; ++j) {
            bh[j] = *reinterpret_cast<const bf16x8*>(&Bh[(wn + j * 16 + lm) * 32 + q * 8]);
            bl[j] = *reinterpret_cast<const bf16x8*>(&Bl[(wn + j * 16 + lm) * 32 + q * 8]);
        }
#pragma unroll
        for (int i = 0; i < 4; ++i)
#pragma unroll
            for (int j = 0; j < 4; ++j) {
                acc[i][j] = __builtin_amdgcn_mfma_f32_16x16x32_bf16(af[i], bl[j], acc[i][j], 0, 0, 0);
                acc[i][j] = __builtin_amdgcn_mfma_f32_16x16x32_bf16(af[i], bh[j], acc[i][j], 0, 0, 0);
            }
        __syncthreads();
    }
    float bv[4];
#pragma unroll
    for (int j = 0; j < 4; ++j) bv[j] = bias[n0 + wn + j * 16 + lm];
#pragma unroll
    for (int j = 0; j < 4; ++j) {
        int col = n0 + wn + j * 16 + lm;
        float s = 0.f, s2 = 0.f;
#pragma unroll
        for (int i = 0; i < 4; ++i) {
            int row0 = m0 + wm + i * 16 + q * 4;
#pragma unroll
            for (int r = 0; r < 4; ++r) {
                int row = row0 + r;
                if (row < M) {
                    float v = acc[i][j][r] + bv[j];
                    if (STATS) { s += v; s2 = fmaf(v, v, s2); }
                    if (RELU) v = fmaxf(v, 0.f);
                    C[(size_t)row * DIM + col] = f2bf(v);
                }
            }
        }
        if (STATS) {
            s += __shfl_xor(s, 16); s += __shfl_xor(s, 32);
            s2 += __shfl_xor(s2, 16); s2 += __shfl_xor(s2, 32);
            if (q == 0) {
                st[0][wid & 1][wn + j * 16 + lm] = s;
                st[1][wid & 1][wn + j * 16 + lm] = s2;
            }
        }
    }
    if (STATS) {
        __syncthreads();
        if (tid < 256) {
            int sel = tid >> 7, cl2 = tid & 127;
            float v = st[sel][0][cl2] + st[sel][1][cl2];
            statsbuf[(size_t)(blockIdx.y * gridDim.x + blockIdx.x) * 256 + sel * 128 + cl2] = v;
        }
    }
}

// ---- stats reduce stage 1: 32 blocks x 512 thr, partial sums over slab chunks
__global__ __launch_bounds__(512) void k_statred1(const float* __restrict__ statsbuf,
                                                  float* __restrict__ spart) {
    int b = blockIdx.x, t = threadIdx.x;     // t = is2*256 + (by*128+cl)
    int is2 = t >> 8, c = t & 255;
    int by = c >> 7, cl = c & 127;
    int x0 = b * 13, x1 = x0 + 13;
    if (x1 > NGB) x1 = NGB;
    float s = 0.f;
    for (int bx = x0; bx < x1; ++bx)
        s += statsbuf[(size_t)(by * NGB + bx) * 256 + is2 * 128 + cl];
    spart[b * 512 + t] = s;
}

// ---- stats reduce stage 2: finalize BN affine  A=gamma*inv, B=beta-mean*A
__global__ void k_statred2(const float* __restrict__ spart, const float* __restrict__ gamma,
                           const float* __restrict__ beta, float* __restrict__ Ap,
                           float* __restrict__ Bp) {
    int c = threadIdx.x;   // 256
    float s = 0.f, s2 = 0.f;
#pragma unroll 8
    for (int b = 0; b < 32; ++b) {
        s += spart[b * 512 + c];
        s2 += spart[b * 512 + 256 + c];
    }
    float mean = s * (1.f / N_NODES);
    float var = s2 * (1.f / N_NODES) - mean * mean;
    float inv = rsqrtf(var + 1e-5f);
    float A = gamma[c] * inv;
    Ap[c] = A;
    Bp[c] = beta[c] - mean * A;
}

// ---- graph mean-pool of relu(A*z+B) (no h write; grid = graphs x 4 splits)
__global__ void k_pool(const unsigned short* __restrict__ z, const float* __restrict__ Ap,
                       const float* __restrict__ Bp, const int* __restrict__ gstart,
                       float* __restrict__ partl) {
    int g = blockIdx.x, sp = blockIdx.y, t = threadIdx.x;
    float A = Ap[t], B = Bp[t];
    int beg = gstart[g], c = gstart[g + 1] - beg;
    int chunk = (c + 3) >> 2;
    int r0 = beg + sp * chunk;
    int r1 = beg + c;
    int rlim = r0 + chunk;
    if (rlim < r1) r1 = rlim;
    float accv = 0.f;
    for (int r = r0; r < r1; ++r)
        accv += fmaxf(fmaf(A, bf2f(z[(size_t)r * DIM + t]), B), 0.f);
    partl[(size_t)(g * 4 + sp) * 256 + t] = accv;
}

// ---- FC head: sums pool partials, divides by cnt, 2-layer MLP
__global__ __launch_bounds__(1024) void k_fc(const float* __restrict__ part,
                                             const int* __restrict__ gstart,
                                             const float* __restrict__ W1,
                                             const float* __restrict__ b1,
                                             const float* __restrict__ W2,
                                             const float* __restrict__ b2,
                                             float* __restrict__ out) {
    __shared__ float gs[DIM * NLAYERS];
    __shared__ float pt[8][128];
    __shared__ float red2[2];
    int g = blockIdx.x, t = threadIdx.x;
    float invc = 1.f / fmaxf((float)(gstart[g + 1] - gstart[g]), 1.f);
    for (int i = t; i < DIM * NLAYERS; i += 1024) {
        int l = i >> 8, c = i & 255;
        const float* pl = part + ((size_t)(l * NGRAPHS + g) * 4) * 256 + c;
        gs[i] = (pl[0] + pl[256] + pl[512] + pl[768]) * invc;
    }
    __syncthreads();
    int o = t & 127, kk = t >> 7;
    float acc = 0.f;
    const float* wp = W1 + (size_t)(kk * 96) * 128 + o;
#pragma unroll 4
    for (int k = 0; k < 96; ++k) acc = fmaf(gs[kk * 96 + k], wp[(size_t)k * 128], acc);
    pt[kk][o] = acc;
    __syncthreads();
    if (t < 128) {
        float v = b1[o];
#pragma unroll
        for (int p = 0; p < 8; ++p) v += pt[p][o];
        v = fmaxf(v, 0.f) * W2[o];
#pragma unroll
        for (int off = 32; off; off >>= 1) v += __shfl_down(v, off, 64);
        if ((t & 63) == 0) red2[t >> 6] = v;
    }
    __syncthreads();
    if (t == 0) out[g] = red2[0] + red2[1] + b2[0];
}

extern "C" void kernel_launch(void* const* d_in, const int* in_sizes, int n_in,
                              void* d_out, int out_size, void* d_ws, size_t ws_size,
                              hipStream_t stream) {
    const float* x = (const float*)d_in[0];
    const int* ei = (const int*)d_in[1];
    const int* batch = (const int*)d_in[2];
    const float* W_enc = (const float*)d_in[4];
    const float* b_enc = (const float*)d_in[5];
    const float* W1 = (const float*)d_in[6];
    const float* b1 = (const float*)d_in[7];
    const float* W2 = (const float*)d_in[8];
    const float* b2 = (const float*)d_in[9];
    const float* gamma = (const float*)d_in[10];
    const float* beta = (const float*)d_in[11];
    const float* Wfc1 = (const float*)d_in[12];
    const float* bfc1 = (const float*)d_in[13];
    const float* Wfc2 = (const float*)d_in[14];
    const float* bfc2 = (const float*)d_in[15];
    float* out = (float*)d_out;
    const int* srcp = ei;
    const int* dstp = ei + N_EDGES;

    // Workspace bump allocator (~110 MB)
    char* w = (char*)d_ws;
    auto alloc = [&](size_t b) -> char* {
        char* p = w;
        w += (b + 255) & ~(size_t)255;
        return p;
    };
    unsigned short* xb   = (unsigned short*)alloc((size_t)N_PAD * F_INPUT * 2);
    unsigned short* hbuf = (unsigned short*)alloc((size_t)N_PAD * DIM * 2);  // enc out; z0 for l>=1
    unsigned short* zA   = (unsigned short*)alloc((size_t)N_PAD * DIM * 2);  // z0@l0 / zbuf
    unsigned short* tbuf = (unsigned short*)alloc((size_t)N_PAD * DIM * 2);  // MLP mid; aliases basep
    unsigned short* wench = (unsigned short*)alloc(F_INPUT * DIM * 2);
    unsigned short* wencl = (unsigned short*)alloc(F_INPUT * DIM * 2);
    unsigned short* w1h = (unsigned short*)alloc((size_t)NLAYERS * DIM * DIM * 2);
    unsigned short* w1l = (unsigned short*)alloc((size_t)NLAYERS * DIM * DIM * 2);
    unsigned short* w2h = (unsigned short*)alloc((size_t)NLAYERS * DIM * DIM * 2);
    unsigned short* w2l = (unsigned short*)alloc((size_t)NLAYERS * DIM * DIM * 2);
    int* csr_src = (int*)alloc((size_t)(N_EDGES + 3 * N_NODES) * 4);
    int* row_ptr = (int*)alloc((size_t)(N_NODES + 1) * 4);
    unsigned* slab = (unsigned*)alloc((size_t)NBH * 25000 * 4);
    int* deg = (int*)alloc((size_t)N_NODES * 4);
    int* gstart = (int*)alloc((NGRAPHS + 1) * 4);
    int* bsum = (int*)alloc(256 * 4);
    int* boff = (int*)alloc(256 * 4);
    float* statsbuf = (float*)alloc((size_t)2 * NGB * 256 * 4);
    float* spart = (float*)alloc((size_t)32 * 512 * 4);
    float* Abn = (float*)alloc(256 * 4);
    float* Bbn = (float*)alloc(256 * 4);
    float* part = (float*)alloc((size_t)NLAYERS * NGRAPHS * 4 * 256 * 4);
    // basep (12.8 MB) aliases tbuf (25.6 MB): basep's lifetime (k_base..k_fill2) ends
    // before tbuf's first write (GEMM-1 of layer 0).
    int* basep = (int*)tbuf;

    // zero the dummy row (index N_NODES) of hbuf so pad edges add exact 0 in the plain agg
    hipMemsetAsync(hbuf + (size_t)N_NODES * DIM, 0, DIM * 2, stream);

    // prep: weights hi/lo + x->bf16 (6250 blocks: x-conversion bound)
    k_prep<<<6250, 256, 0, stream>>>(W_enc, W1, W2, x, wench, wencl, w1h, w1l, w2h, w2l, xb);

    // CSR build, atomic-free
    const int NB = (N_NODES + 255) / 256;  // 196
    k_count<<<NBH, 512, 0, stream>>>(dstp, slab);
    k_degred<<<NB, 256, 0, stream>>>(slab, batch, deg, gstart);
    k_scan1<<<NB, 256, 0, stream>>>(deg, row_ptr + 1, bsum);
    k_scan2<<<1, 256, 0, stream>>>(bsum, boff, NB);
    k_scan3<<<NB, 256, 0, stream>>>(row_ptr, boff);
    k_base<<<NB, 256, 0, stream>>>(slab, row_ptr, basep, csr_src);
    k_fill2<<<NBH, 512, 0, stream>>>(srcp, dstp, basep, csr_src);

    // encoder: h = x @ W_enc + b_enc
    dim3 ggrid(NGB, 2);
    k_gemm<F_INPUT, false, false><<<ggrid, 256, 0, stream>>>(xb, wench, wencl, b_enc, hbuf,
                                                             nullptr, N_NODES);

    dim3 pgrid(NGRAPHS, 4);
    for (int l = 0; l < NLAYERS; ++l) {
        // agg: layer 0 reads raw enc output (hbuf); layers 1,2 read zbuf (zA) with fused BN.
        const unsigned short* aggin = (l == 0) ? hbuf : zA;
        unsigned short* aggout = (l == 0) ? zA : hbuf;
        if (l == 0)
            k_agg<false><<<6250, 256, 0, stream>>>(aggin, row_ptr, csr_src, nullptr, nullptr, aggout);
        else
            k_agg<true><<<6250, 256, 0, stream>>>(aggin, row_ptr, csr_src, Abn, Bbn, aggout);
        k_gemm<DIM, true, false><<<ggrid, 256, 0, stream>>>(aggout, w1h + l * 65536, w1l + l * 65536,
                                                            b1 + l * DIM, tbuf, nullptr, N_NODES);
        k_gemm<DIM, false, true><<<ggrid, 256, 0, stream>>>(tbuf, w2h + l * 65536, w2l + l * 65536,
                                                            b2 + l * DIM, zA, statsbuf, N_NODES);
        k_statred1<<<32, 512, 0, stream>>>(statsbuf, spart);
        k_statred2<<<1, 256, 0, stream>>>(spart, gamma + l * DIM, beta + l * DIM, Abn, Bbn);
        k_pool<<<pgrid, 256, 0, stream>>>(zA, Abn, Bbn, gstart, part + (size_t)l * NGRAPHS * 4 * 256);
    }
    k_fc<<<NGRAPHS, 1024, 0, stream>>>(part, gstart, Wfc1, bfc1, Wfc2, bfc2, out);
}